// Round 16
// baseline (87.315 us; speedup 1.0000x reference)
//
#include <hip/hip_runtime.h>
#include <hip/hip_bf16.h>
#include <math.h>

#define B_ 2
#define T_ 512
#define D_ 64

typedef __attribute__((ext_vector_type(8))) short bf16x8;
typedef __attribute__((ext_vector_type(8))) unsigned short u16x8;
typedef __attribute__((ext_vector_type(8))) short s16x8;
typedef __attribute__((ext_vector_type(4))) float f32x4;

static __device__ __forceinline__ unsigned short f2bf(float v) {
    __hip_bfloat16 h = __float2bfloat16(v);
    return *reinterpret_cast<unsigned short*>(&h);
}
static __device__ __forceinline__ float bf2f(unsigned short u) {
    return __uint_as_float(((unsigned)u) << 16);
}
static __device__ __forceinline__ unsigned short maxbits(unsigned short a, unsigned short b) {
    float m = fmaxf(bf2f(a), bf2f(b));
    return (unsigned short)(__float_as_uint(m) >> 16);
}
static __device__ __forceinline__ unsigned short minbits(unsigned short a, unsigned short b) {
    float m = fminf(bf2f(a), bf2f(b));
    return (unsigned short)(__float_as_uint(m) >> 16);
}

// ---- order-isomorphic key space: unsigned compare on keys == float compare ----
static __device__ __forceinline__ u16x8 tokey8(u16x8 v) {
    s16x8 sr = (s16x8)v >> 15;
    u16x8 m = (u16x8)sr | (unsigned short)0x8000;
    return v ^ m;
}
static __device__ __forceinline__ u16x8 fromkey8(u16x8 k) {
    s16x8 sr = (s16x8)k >> 15;
    u16x8 m = ((u16x8)(~sr) & (unsigned short)0x7FFF) | (unsigned short)0x8000;
    return k ^ m;
}
static __device__ __forceinline__ u16x8 kmax8(u16x8 a, u16x8 b) {
    return __builtin_elementwise_max(a, b);
}
static __device__ __forceinline__ u16x8 kmin8(u16x8 a, u16x8 b) {
    return __builtin_elementwise_min(a, b);
}

// ---------------------------------------------------------------------------
// Fused prep (43 heterogeneous blocks, 512 threads):
//  [0,8)   sparse tables tab[k][b][t][c], k=0..9, bf16 KEY space
//  [8,11)  W r-part fragment pack (rows C..C+128, 16 frags/layer)
//  [11,43) intra[b][jt][jj][128] running max/min within 32-j tile, KEY space
// (No zero-init: atomicMax always beats the 0xAA poison and is idempotent.)
// ---------------------------------------------------------------------------
__global__ __launch_bounds__(512) void prep_kernel(
    const float* __restrict__ f,
    const float* __restrict__ W0, const float* __restrict__ W1, const float* __restrict__ W2,
    unsigned short* __restrict__ tmax, unsigned short* __restrict__ tmin,
    unsigned short* __restrict__ wf,
    unsigned short* __restrict__ intra) {

    __shared__ unsigned short lmax[512][16];
    __shared__ unsigned short lmin[512][16];

    const int blk = blockIdx.x;
    const int tid = threadIdx.x;

    if (blk < 8) {
        const int b = blk & 1;
        const int c0 = (blk >> 1) * 16;
        const int t = tid;

        u16x8 mx[2], mn[2];
#pragma unroll
        for (int h = 0; h < 2; ++h) {
            const float* fp = &f[((size_t)(b * T_ + t) << 6) + c0 + h * 8];
#pragma unroll
            for (int e = 0; e < 8; ++e) {
                unsigned short u = f2bf(fp[e]);
                mx[h][e] = u; mn[h][e] = u;
            }
            size_t base = ((size_t)(b * T_ + t) << 6) + c0 + h * 8;
            *reinterpret_cast<u16x8*>(&tmax[base]) = tokey8(mx[h]);
            *reinterpret_cast<u16x8*>(&tmin[base]) = tokey8(mn[h]);
        }
        for (int k = 1; k <= 9; ++k) {
            *reinterpret_cast<u16x8*>(&lmax[t][0]) = mx[0];
            *reinterpret_cast<u16x8*>(&lmax[t][8]) = mx[1];
            *reinterpret_cast<u16x8*>(&lmin[t][0]) = mn[0];
            *reinterpret_cast<u16x8*>(&lmin[t][8]) = mn[1];
            __syncthreads();
            int t2 = t + (1 << (k - 1));
            if (t2 > T_ - 1) t2 = T_ - 1;
            u16x8 qx0 = *reinterpret_cast<const u16x8*>(&lmax[t2][0]);
            u16x8 qx1 = *reinterpret_cast<const u16x8*>(&lmax[t2][8]);
            u16x8 qn0 = *reinterpret_cast<const u16x8*>(&lmin[t2][0]);
            u16x8 qn1 = *reinterpret_cast<const u16x8*>(&lmin[t2][8]);
#pragma unroll
            for (int e = 0; e < 8; ++e) {
                mx[0][e] = maxbits(mx[0][e], qx0[e]);
                mx[1][e] = maxbits(mx[1][e], qx1[e]);
                mn[0][e] = minbits(mn[0][e], qn0[e]);
                mn[1][e] = minbits(mn[1][e], qn1[e]);
            }
            size_t base = ((size_t)((k * B_ + b) * T_ + t) << 6) + c0;
            *reinterpret_cast<u16x8*>(&tmax[base]) = tokey8(mx[0]);
            *reinterpret_cast<u16x8*>(&tmax[base + 8]) = tokey8(mx[1]);
            *reinterpret_cast<u16x8*>(&tmin[base]) = tokey8(mn[0]);
            *reinterpret_cast<u16x8*>(&tmin[base + 8]) = tokey8(mn[1]);
            __syncthreads();
        }
    } else if (blk < 11) {
        const int layer = blk - 8;
        const float* W = (layer == 0) ? W0 : ((layer == 1) ? W1 : W2);
        const int Coff = (layer == 0) ? 128 : 64;
        const int l = tid & 63;
#pragma unroll
        for (int q = 0; q < 2; ++q) {
            int fr = (tid >> 6) + q * 8;          // 0..15
            int kt = fr >> 2, nt = fr & 3;
#pragma unroll
            for (int e = 0; e < 8; ++e) {
                int row = Coff + kt * 32 + ((l >> 4) << 3) + e;
                int col = nt * 16 + (l & 15);
                wf[((size_t)(layer * 16 + fr) * 64 + l) * 8 + e] = f2bf(W[row * 64 + col]);
            }
        }
    } else {
        const int x = blk - 11;
        const int jt = x & 15, b = x >> 4;
        const int jj = tid >> 4, c8 = tid & 15;
        const bool ismin = c8 >= 8;
        unsigned short (*sc)[128] = reinterpret_cast<unsigned short (*)[128]>(lmax);

        const float* fp = &f[((size_t)(b * T_ + jt * 32 + jj) << 6) + (c8 & 7) * 8];
        u16x8 r;
#pragma unroll
        for (int e = 0; e < 8; ++e) r[e] = f2bf(fp[e]);

#pragma unroll
        for (int off = 1; off < 32; off <<= 1) {
            *reinterpret_cast<u16x8*>(&sc[jj][c8 * 8]) = r;
            __syncthreads();
            if (jj >= off) {
                u16x8 q = *reinterpret_cast<const u16x8*>(&sc[jj - off][c8 * 8]);
#pragma unroll
                for (int e = 0; e < 8; ++e)
                    r[e] = ismin ? minbits(r[e], q[e]) : maxbits(r[e], q[e]);
            }
            __syncthreads();
        }
        *reinterpret_cast<u16x8*>(&intra[((size_t)((b * 16 + jt) * 32 + jj) << 7) + c8 * 8]) = tokey8(r);
    }
}

// ---------------------------------------------------------------------------
// g0[b,t,o] = bias[o] + sum_{c<128} cur0[b,t,c] * W0[c][o]
// ---------------------------------------------------------------------------
__global__ __launch_bounds__(256) void g0_kernel(
    const unsigned short* __restrict__ tabmax,
    const unsigned short* __restrict__ tabmin,
    const float* __restrict__ W0, const float* __restrict__ bias,
    float* __restrict__ g) {

    __shared__ float cur_lds[4][128];

    const int tid = threadIdx.x;
    const int bt0 = blockIdx.x * 4;

    if (tid < 64) {
        int isel = tid >> 4, c8 = tid & 15;
        int bt = bt0 + isel;
        int b = bt >> 9, t = bt & 511;
        int len = T_ - t;
        int kk = 31 - __clz(len);
        int t2 = T_ - (1 << kk);
        const unsigned short* tab = (c8 < 8) ? tabmax : tabmin;
        int cc = (c8 & 7) * 8;
        u16x8 va = *reinterpret_cast<const u16x8*>(&tab[(((size_t)(kk * B_ + b) * T_ + t) << 6) + cc]);
        u16x8 vb = *reinterpret_cast<const u16x8*>(&tab[(((size_t)(kk * B_ + b) * T_ + t2) << 6) + cc]);
        u16x8 rv = fromkey8((c8 < 8) ? kmax8(va, vb) : kmin8(va, vb));
#pragma unroll
        for (int e = 0; e < 8; ++e)
            cur_lds[isel][c8 * 8 + e] = bf2f(rv[e]);
    }
    __syncthreads();

    const int r = tid >> 6, o = tid & 63;
    float s = bias[o];
#pragma unroll 8
    for (int c = 0; c < 128; ++c)
        s = fmaf(cur_lds[r][c], W0[c * 64 + o], s);
    g[((size_t)(bt0 + r) << 6) + o] = s;
}

// ---------------------------------------------------------------------------
// g[b,t,o] = bias[o] + sum_{c<64} cur[b,t,c] * W[c][o]   (fp32 cur)
// ---------------------------------------------------------------------------
__global__ __launch_bounds__(256) void g64_kernel(
    const float* __restrict__ cur, const float* __restrict__ W,
    const float* __restrict__ bias, float* __restrict__ g) {
    const int bt = blockIdx.x * 4 + (threadIdx.x >> 6);
    const int o = threadIdx.x & 63;
    float s = bias[o];
    const float* cp = &cur[(size_t)bt << 6];
#pragma unroll 8
    for (int c = 0; c < 64; ++c)
        s = fmaf(cp[c], W[c * 64 + o], s);
    g[((size_t)bt << 6) + o] = s;
}

// ---------------------------------------------------------------------------
// Pair GEMM, K = 128.  Block = 1024 threads = 16 waves; (b, 8 i's, 32 j's).
// Wave w owns (i = i0 + (w>>1), nt-half = w&1): acc[2][2] = 16 VGPR.
// __launch_bounds__(1024, 8) pins VGPR <= 64 -> 8 waves/SIMD (2 blocks/CU,
// 32 waves/CU).  Key-space combine; g added in epilogue; atomicMax output.
// ---------------------------------------------------------------------------
__global__ __launch_bounds__(1024, 8) void pair_kernel(
    const unsigned short* __restrict__ tabmax,
    const unsigned short* __restrict__ tabmin,
    const unsigned short* __restrict__ intra,   // [B,16,32,128] keys
    const unsigned short* __restrict__ wf,      // layer base, 16 frags (values)
    const float* __restrict__ g,                // [B,T,64] fp32
    float* __restrict__ out) {

    // ---- decode: diag blocks first (m < 128, b-interleaved), then non-diag ----
    int m = blockIdx.x;
    int b, jt, it;
    bool diag;
    if (m < 128) {
        diag = true;
        b = m & 1;
        int idx = m >> 1;
        jt = idx >> 2;
        it = 4 * jt + (idx & 3);
    } else {
        diag = false;
        int m2 = m - 128;
        b = m2 & 1;
        int m3 = m2 >> 1;
        jt = 1;
        while (m3 >= 2 * jt * (jt + 1)) ++jt;
        it = m3 - 2 * jt * (jt - 1);
    }
    const int i0 = it * 8, j0 = jt * 32;

    const int tid = threadIdx.x;
    const int l = tid & 63, w = tid >> 6;         // w = 0..15
    const int lg = l >> 4, li = l & 15;
    const int iloc = w >> 1;                      // 0..7
    const int nth = w & 1;                        // nt-half
    const int pi = i0 + iloc;

    __shared__ unsigned short intr[32][136];
    __shared__ unsigned short pref[8][136];
    __shared__ unsigned short wlds[16 * 64 * 8];   // 16 KB
    __shared__ float gl[32][68];

    // ---- staging (role-split across 1024 threads) ----
    {   // W: one 16B chunk per thread (1024 chunks)
        u16x8 v = *reinterpret_cast<const u16x8*>(&wf[(size_t)tid * 8]);
        *reinterpret_cast<u16x8*>(&wlds[tid * 8]) = v;
    }
    if (tid < 512) {        // g tile [32][64] as float4 (512 chunks)
        int jj = tid >> 4, c4 = tid & 15;
        float4 v = *reinterpret_cast<const float4*>(&g[((size_t)(b * T_ + j0 + jj) << 6) + c4 * 4]);
        *reinterpret_cast<float4*>(&gl[jj][c4 * 4]) = v;
    }
    if (!diag) {
        if (tid >= 512) {   // intra tile (512 chunks), key space
            int t = tid - 512;
            int jj = t >> 4, c8 = t & 15;
            u16x8 v = *reinterpret_cast<const u16x8*>(
                &intra[((size_t)((b * 16 + jt) * 32 + jj) << 7) + c8 * 8]);
            *reinterpret_cast<u16x8*>(&intr[jj][c8 * 8]) = v;
        }
        if (tid < 128) {    // prefix queries: 8 i's x 16 chunks, key space
            int isel = tid >> 4, c8 = tid & 15;
            int i = i0 + isel;
            int len = j0 - i;                  // >= 1 (non-diag)
            int kk = 31 - __clz(len);
            int t2 = j0 - (1 << kk);
            const unsigned short* tab = (c8 < 8) ? tabmax : tabmin;
            int cc = (c8 & 7) * 8;
            u16x8 va = *reinterpret_cast<const u16x8*>(&tab[(((size_t)(kk * B_ + b) * T_ + i) << 6) + cc]);
            u16x8 vb = *reinterpret_cast<const u16x8*>(&tab[(((size_t)(kk * B_ + b) * T_ + t2) << 6) + cc]);
            u16x8 r = (c8 < 8) ? kmax8(va, vb) : kmin8(va, vb);
            *reinterpret_cast<u16x8*>(&pref[isel][c8 * 8]) = r;
        }
    }
    __syncthreads();

    // ---- diag query params (per s) ----
    int kk_q[2], t2_q[2];
    if (diag) {
#pragma unroll
        for (int s = 0; s < 2; ++s) {
            int pj = j0 + 16 * s + li;
            int je = (pj < pi) ? pi : pj;
            int len = je - pi + 1;
            kk_q[s] = 31 - __clz(len);
            t2_q[s] = je + 1 - (1 << kk_q[s]);
        }
    }

    // ---- GEMM: K=128, 4 k-tiles; acc[s][ntl] ----
    f32x4 acc[2][2];
#pragma unroll
    for (int s = 0; s < 2; ++s)
#pragma unroll
        for (int ntl = 0; ntl < 2; ++ntl) acc[s][ntl] = (f32x4){0.f, 0.f, 0.f, 0.f};

#pragma unroll
    for (int krt = 0; krt < 4; ++krt) {
        bf16x8 av[2];
        if (!diag) {
            u16x8 pv = *reinterpret_cast<const u16x8*>(&pref[iloc][(krt * 4 + lg) * 8]);
#pragma unroll
            for (int s = 0; s < 2; ++s) {
                u16x8 iv = *reinterpret_cast<const u16x8*>(&intr[16 * s + li][(krt * 4 + lg) * 8]);
                u16x8 ck = (krt < 2) ? kmax8(iv, pv) : kmin8(iv, pv);
                av[s] = (bf16x8)fromkey8(ck);
            }
        } else {
            const int c8 = krt * 4 + lg;
            const unsigned short* tab = (krt < 2) ? tabmax : tabmin;
            const int cc = (c8 & 7) * 8;
#pragma unroll
            for (int s = 0; s < 2; ++s) {
                u16x8 va = *reinterpret_cast<const u16x8*>(&tab[(((size_t)(kk_q[s] * B_ + b) * T_ + pi) << 6) + cc]);
                u16x8 vb = *reinterpret_cast<const u16x8*>(&tab[(((size_t)(kk_q[s] * B_ + b) * T_ + t2_q[s]) << 6) + cc]);
                u16x8 ck = (krt < 2) ? kmax8(va, vb) : kmin8(va, vb);
                av[s] = (bf16x8)fromkey8(ck);
            }
        }
#pragma unroll
        for (int ntl = 0; ntl < 2; ++ntl) {
            bf16x8 wfr = *reinterpret_cast<const bf16x8*>(
                &wlds[((krt * 4 + 2 * nth + ntl) * 64 + l) * 8]);
            acc[0][ntl] = __builtin_amdgcn_mfma_f32_16x16x32_bf16(av[0], wfr, acc[0][ntl], 0, 0, 0);
            acc[1][ntl] = __builtin_amdgcn_mfma_f32_16x16x32_bf16(av[1], wfr, acc[1][ntl], 0, 0, 0);
        }
    }

    // ---- epilogue: vm = max over valid jj of (acc + g[j]); sigmoid; atomicMax ----
#pragma unroll
    for (int ntl = 0; ntl < 2; ++ntl) {
        const int o = (2 * nth + ntl) * 16 + li;
        float vm = -1e9f;
#pragma unroll
        for (int s = 0; s < 2; ++s)
#pragma unroll
            for (int r = 0; r < 4; ++r) {
                int jj = 16 * s + lg * 4 + r;
                float v = acc[s][ntl][r] + gl[jj][o];
                if (!diag || (j0 + jj >= pi)) vm = fmaxf(vm, v);
            }
        vm = fmaxf(vm, __shfl_xor(vm, 16));
        vm = fmaxf(vm, __shfl_xor(vm, 32));
        if (l < 16) {
            float h = 1.0f / (1.0f + __expf(-vm));
            atomicMax((int*)out + (((size_t)(b * T_ + pi) << 6) + o), __float_as_int(h));
        }
    }
}

// ---------------------------------------------------------------------------
extern "C" void kernel_launch(void* const* d_in, const int* in_sizes, int n_in,
                              void* d_out, int out_size, void* d_ws, size_t ws_size,
                              hipStream_t stream) {
    const float* f  = (const float*)d_in[0];
    const float* W0 = (const float*)d_in[1];
    const float* b0 = (const float*)d_in[2];
    const float* W1 = (const float*)d_in[3];
    const float* b1 = (const float*)d_in[4];
    const float* W2 = (const float*)d_in[5];
    const float* b2 = (const float*)d_in[6];
    float* outp = (float*)d_out;

    // workspace layout
    unsigned short* tabmax = (unsigned short*)d_ws;               // 10*B*T*64
    unsigned short* tabmin = tabmax + 10 * B_ * T_ * 64;          // 10*B*T*64
    unsigned short* wf     = tabmin + 10 * B_ * T_ * 64;          // 3*16*64*8
    unsigned short* intra  = wf + 3 * 16 * 64 * 8;                // B*16*32*128
    float* cur1 = (float*)(intra + B_ * 16 * 32 * 128);           // [B,T,64]
    float* cur2 = cur1 + B_ * T_ * 64;                            // [B,T,64]
    float* gbuf = cur2 + B_ * T_ * 64;                            // [B,T,64]

    prep_kernel<<<dim3(43), dim3(512), 0, stream>>>(f, W0, W1, W2,
                                                    tabmax, tabmin, wf, intra);

    const dim3 pgrid(B_ * 544);
    const dim3 ggrid(B_ * T_ / 4);

    g0_kernel<<<ggrid, dim3(256), 0, stream>>>(tabmax, tabmin, W0, b0, gbuf);
    pair_kernel<<<pgrid, dim3(1024), 0, stream>>>(tabmax, tabmin, intra,
                                                  wf + 0 * 8192, gbuf, cur1);

    g64_kernel<<<ggrid, dim3(256), 0, stream>>>(cur1, W1, b1, gbuf);
    pair_kernel<<<pgrid, dim3(1024), 0, stream>>>(tabmax, tabmin, intra,
                                                  wf + 1 * 8192, gbuf, cur2);

    g64_kernel<<<ggrid, dim3(256), 0, stream>>>(cur2, W2, b2, gbuf);
    pair_kernel<<<pgrid, dim3(1024), 0, stream>>>(tabmax, tabmin, intra,
                                                  wf + 2 * 8192, gbuf, outp);
}

// Round 17
// 75.279 us; speedup vs baseline: 1.1599x; 1.1599x over previous
//
#include <hip/hip_runtime.h>
#include <hip/hip_bf16.h>
#include <math.h>

#define B_ 2
#define T_ 512
#define D_ 64

typedef __attribute__((ext_vector_type(8))) short bf16x8;
typedef __attribute__((ext_vector_type(8))) unsigned short u16x8;
typedef __attribute__((ext_vector_type(8))) short s16x8;
typedef __attribute__((ext_vector_type(4))) float f32x4;

static __device__ __forceinline__ unsigned short f2bf(float v) {
    __hip_bfloat16 h = __float2bfloat16(v);
    return *reinterpret_cast<unsigned short*>(&h);
}
static __device__ __forceinline__ float bf2f(unsigned short u) {
    return __uint_as_float(((unsigned)u) << 16);
}
static __device__ __forceinline__ unsigned short maxbits(unsigned short a, unsigned short b) {
    float m = fmaxf(bf2f(a), bf2f(b));
    return (unsigned short)(__float_as_uint(m) >> 16);
}
static __device__ __forceinline__ unsigned short minbits(unsigned short a, unsigned short b) {
    float m = fminf(bf2f(a), bf2f(b));
    return (unsigned short)(__float_as_uint(m) >> 16);
}

// ---- order-isomorphic key space: unsigned compare on keys == float compare ----
static __device__ __forceinline__ u16x8 tokey8(u16x8 v) {
    s16x8 sr = (s16x8)v >> 15;
    u16x8 m = (u16x8)sr | (unsigned short)0x8000;
    return v ^ m;
}
static __device__ __forceinline__ u16x8 fromkey8(u16x8 k) {
    s16x8 sr = (s16x8)k >> 15;
    u16x8 m = ((u16x8)(~sr) & (unsigned short)0x7FFF) | (unsigned short)0x8000;
    return k ^ m;
}
static __device__ __forceinline__ u16x8 kmax8(u16x8 a, u16x8 b) {
    return __builtin_elementwise_max(a, b);
}
static __device__ __forceinline__ u16x8 kmin8(u16x8 a, u16x8 b) {
    return __builtin_elementwise_min(a, b);
}

// ---------------------------------------------------------------------------
// Fused prep (43 heterogeneous blocks, 512 threads):
//  [0,8)   sparse tables tab[k][b][t][c], k=0..9, bf16 KEY space
//  [8,11)  W r-part fragment pack (rows C..C+128, 16 frags/layer)
//  [11,43) intra[b][jt][jj][128] running max/min within 32-j tile, KEY space
// (No zero-init: atomicMax (int cmp) always beats the 0xAA poison, which is a
//  negative float; every (b,t,o) is covered by its diagonal tile; idempotent.)
// ---------------------------------------------------------------------------
__global__ __launch_bounds__(512) void prep_kernel(
    const float* __restrict__ f,
    const float* __restrict__ W0, const float* __restrict__ W1, const float* __restrict__ W2,
    unsigned short* __restrict__ tmax, unsigned short* __restrict__ tmin,
    unsigned short* __restrict__ wf,
    unsigned short* __restrict__ intra) {

    __shared__ unsigned short lmax[512][16];
    __shared__ unsigned short lmin[512][16];

    const int blk = blockIdx.x;
    const int tid = threadIdx.x;

    if (blk < 8) {
        const int b = blk & 1;
        const int c0 = (blk >> 1) * 16;
        const int t = tid;

        u16x8 mx[2], mn[2];
#pragma unroll
        for (int h = 0; h < 2; ++h) {
            const float* fp = &f[((size_t)(b * T_ + t) << 6) + c0 + h * 8];
#pragma unroll
            for (int e = 0; e < 8; ++e) {
                unsigned short u = f2bf(fp[e]);
                mx[h][e] = u; mn[h][e] = u;
            }
            size_t base = ((size_t)(b * T_ + t) << 6) + c0 + h * 8;
            *reinterpret_cast<u16x8*>(&tmax[base]) = tokey8(mx[h]);
            *reinterpret_cast<u16x8*>(&tmin[base]) = tokey8(mn[h]);
        }
        for (int k = 1; k <= 9; ++k) {
            *reinterpret_cast<u16x8*>(&lmax[t][0]) = mx[0];
            *reinterpret_cast<u16x8*>(&lmax[t][8]) = mx[1];
            *reinterpret_cast<u16x8*>(&lmin[t][0]) = mn[0];
            *reinterpret_cast<u16x8*>(&lmin[t][8]) = mn[1];
            __syncthreads();
            int t2 = t + (1 << (k - 1));
            if (t2 > T_ - 1) t2 = T_ - 1;
            u16x8 qx0 = *reinterpret_cast<const u16x8*>(&lmax[t2][0]);
            u16x8 qx1 = *reinterpret_cast<const u16x8*>(&lmax[t2][8]);
            u16x8 qn0 = *reinterpret_cast<const u16x8*>(&lmin[t2][0]);
            u16x8 qn1 = *reinterpret_cast<const u16x8*>(&lmin[t2][8]);
#pragma unroll
            for (int e = 0; e < 8; ++e) {
                mx[0][e] = maxbits(mx[0][e], qx0[e]);
                mx[1][e] = maxbits(mx[1][e], qx1[e]);
                mn[0][e] = minbits(mn[0][e], qn0[e]);
                mn[1][e] = minbits(mn[1][e], qn1[e]);
            }
            size_t base = ((size_t)((k * B_ + b) * T_ + t) << 6) + c0;
            *reinterpret_cast<u16x8*>(&tmax[base]) = tokey8(mx[0]);
            *reinterpret_cast<u16x8*>(&tmax[base + 8]) = tokey8(mx[1]);
            *reinterpret_cast<u16x8*>(&tmin[base]) = tokey8(mn[0]);
            *reinterpret_cast<u16x8*>(&tmin[base + 8]) = tokey8(mn[1]);
            __syncthreads();
        }
    } else if (blk < 11) {
        const int layer = blk - 8;
        const float* W = (layer == 0) ? W0 : ((layer == 1) ? W1 : W2);
        const int Coff = (layer == 0) ? 128 : 64;
        const int l = tid & 63;
#pragma unroll
        for (int q = 0; q < 2; ++q) {
            int fr = (tid >> 6) + q * 8;          // 0..15
            int kt = fr >> 2, nt = fr & 3;
#pragma unroll
            for (int e = 0; e < 8; ++e) {
                int row = Coff + kt * 32 + ((l >> 4) << 3) + e;
                int col = nt * 16 + (l & 15);
                wf[((size_t)(layer * 16 + fr) * 64 + l) * 8 + e] = f2bf(W[row * 64 + col]);
            }
        }
    } else {
        const int x = blk - 11;
        const int jt = x & 15, b = x >> 4;
        const int jj = tid >> 4, c8 = tid & 15;
        const bool ismin = c8 >= 8;
        unsigned short (*sc)[128] = reinterpret_cast<unsigned short (*)[128]>(lmax);

        const float* fp = &f[((size_t)(b * T_ + jt * 32 + jj) << 6) + (c8 & 7) * 8];
        u16x8 r;
#pragma unroll
        for (int e = 0; e < 8; ++e) r[e] = f2bf(fp[e]);

#pragma unroll
        for (int off = 1; off < 32; off <<= 1) {
            *reinterpret_cast<u16x8*>(&sc[jj][c8 * 8]) = r;
            __syncthreads();
            if (jj >= off) {
                u16x8 q = *reinterpret_cast<const u16x8*>(&sc[jj - off][c8 * 8]);
#pragma unroll
                for (int e = 0; e < 8; ++e)
                    r[e] = ismin ? minbits(r[e], q[e]) : maxbits(r[e], q[e]);
            }
            __syncthreads();
        }
        *reinterpret_cast<u16x8*>(&intra[((size_t)((b * 16 + jt) * 32 + jj) << 7) + c8 * 8]) = tokey8(r);
    }
}

// ---------------------------------------------------------------------------
// g0[b,t,o] = bias[o] + sum_{c<128} cur0[b,t,c] * W0[c][o]
// ---------------------------------------------------------------------------
__global__ __launch_bounds__(256) void g0_kernel(
    const unsigned short* __restrict__ tabmax,
    const unsigned short* __restrict__ tabmin,
    const float* __restrict__ W0, const float* __restrict__ bias,
    float* __restrict__ g) {

    __shared__ float cur_lds[4][128];

    const int tid = threadIdx.x;
    const int bt0 = blockIdx.x * 4;

    if (tid < 64) {
        int isel = tid >> 4, c8 = tid & 15;
        int bt = bt0 + isel;
        int b = bt >> 9, t = bt & 511;
        int len = T_ - t;
        int kk = 31 - __clz(len);
        int t2 = T_ - (1 << kk);
        const unsigned short* tab = (c8 < 8) ? tabmax : tabmin;
        int cc = (c8 & 7) * 8;
        u16x8 va = *reinterpret_cast<const u16x8*>(&tab[(((size_t)(kk * B_ + b) * T_ + t) << 6) + cc]);
        u16x8 vb = *reinterpret_cast<const u16x8*>(&tab[(((size_t)(kk * B_ + b) * T_ + t2) << 6) + cc]);
        u16x8 rv = fromkey8((c8 < 8) ? kmax8(va, vb) : kmin8(va, vb));
#pragma unroll
        for (int e = 0; e < 8; ++e)
            cur_lds[isel][c8 * 8 + e] = bf2f(rv[e]);
    }
    __syncthreads();

    const int r = tid >> 6, o = tid & 63;
    float s = bias[o];
#pragma unroll 8
    for (int c = 0; c < 128; ++c)
        s = fmaf(cur_lds[r][c], W0[c * 64 + o], s);
    g[((size_t)(bt0 + r) << 6) + o] = s;
}

// ---------------------------------------------------------------------------
// g[b,t,o] = bias[o] + sum_{c<64} cur[b,t,c] * W[c][o]   (fp32 cur)
// ---------------------------------------------------------------------------
__global__ __launch_bounds__(256) void g64_kernel(
    const float* __restrict__ cur, const float* __restrict__ W,
    const float* __restrict__ bias, float* __restrict__ g) {
    const int bt = blockIdx.x * 4 + (threadIdx.x >> 6);
    const int o = threadIdx.x & 63;
    float s = bias[o];
    const float* cp = &cur[(size_t)bt << 6];
#pragma unroll 8
    for (int c = 0; c < 64; ++c)
        s = fmaf(cp[c], W[c * 64 + o], s);
    g[((size_t)bt << 6) + o] = s;
}

// ---------------------------------------------------------------------------
// Pair GEMM, K = 128 (r-part only).  Block = 512 threads = 8 waves;
// (b, 8 i's, 32 j's); wave w owns row i = i0+w.  A-operand combine done in
// key space (packed u16 max/min + vector back-transform).  g added in the
// epilogue before the max; atomicMax(sigmoid) to out.  Diag blocks first.
// ---------------------------------------------------------------------------
__global__ __launch_bounds__(512) void pair_kernel(
    const unsigned short* __restrict__ tabmax,
    const unsigned short* __restrict__ tabmin,
    const unsigned short* __restrict__ intra,   // [B,16,32,128] keys
    const unsigned short* __restrict__ wf,      // layer base, 16 frags (values)
    const float* __restrict__ g,                // [B,T,64] fp32
    float* __restrict__ out) {

    // ---- decode: diag blocks first (m < 128, b-interleaved), then non-diag ----
    int m = blockIdx.x;
    int b, jt, it;
    bool diag;
    if (m < 128) {
        diag = true;
        b = m & 1;
        int idx = m >> 1;            // 0..63
        jt = idx >> 2;
        it = 4 * jt + (idx & 3);
    } else {
        diag = false;
        int m2 = m - 128;
        b = m2 & 1;
        int m3 = m2 >> 1;            // 0..479
        jt = 1;
        while (m3 >= 2 * jt * (jt + 1)) ++jt;     // <=14 iters
        it = m3 - 2 * jt * (jt - 1);              // 0 .. 4*jt-1
    }
    const int i0 = it * 8, j0 = jt * 32;

    const int tid = threadIdx.x;
    const int l = tid & 63, w = tid >> 6;         // w = 0..7
    const int lg = l >> 4, li = l & 15;
    const int pi = i0 + w;

    __shared__ unsigned short intr[32][136];
    __shared__ unsigned short pref[8][136];
    __shared__ unsigned short wlds[16 * 64 * 8];   // 16 KB
    __shared__ float gl[32][68];

    // ---- stage W fragments (contiguous, 1024 chunks) ----
#pragma unroll
    for (int q = 0; q < 2; ++q) {
        int idx = q * 512 + tid;
        u16x8 v = *reinterpret_cast<const u16x8*>(&wf[(size_t)idx * 8]);
        *reinterpret_cast<u16x8*>(&wlds[idx * 8]) = v;
    }

    // ---- stage g tile [32 j][64 o] (512 float4 chunks) ----
    {
        int jj = tid >> 4, c4 = tid & 15;
        float4 v = *reinterpret_cast<const float4*>(&g[((size_t)(b * T_ + j0 + jj) << 6) + c4 * 4]);
        *reinterpret_cast<float4*>(&gl[jj][c4 * 4]) = v;
    }

    if (!diag) {
        // ---- intra tile: contiguous copy (512 chunks), key space ----
        {
            int jj = tid >> 4, c8 = tid & 15;
            u16x8 v = *reinterpret_cast<const u16x8*>(
                &intra[((size_t)((b * 16 + jt) * 32 + jj) << 7) + c8 * 8]);
            *reinterpret_cast<u16x8*>(&intr[jj][c8 * 8]) = v;
        }
        // ---- prefix queries: 8 i's x 16 chunks, range [i, j0-1], key space ----
        if (tid < 128) {
            int isel = tid >> 4, c8 = tid & 15;
            int i = i0 + isel;
            int len = j0 - i;                  // >= 1 (non-diag)
            int kk = 31 - __clz(len);
            int t2 = j0 - (1 << kk);
            const unsigned short* tab = (c8 < 8) ? tabmax : tabmin;
            int cc = (c8 & 7) * 8;
            u16x8 va = *reinterpret_cast<const u16x8*>(&tab[(((size_t)(kk * B_ + b) * T_ + i) << 6) + cc]);
            u16x8 vb = *reinterpret_cast<const u16x8*>(&tab[(((size_t)(kk * B_ + b) * T_ + t2) << 6) + cc]);
            u16x8 r = (c8 < 8) ? kmax8(va, vb) : kmin8(va, vb);
            *reinterpret_cast<u16x8*>(&pref[isel][c8 * 8]) = r;
        }
    }
    __syncthreads();

    // ---- diag query params (per s) ----
    int kk_q[2], t2_q[2];
    if (diag) {
#pragma unroll
        for (int s = 0; s < 2; ++s) {
            int pj = j0 + 16 * s + li;
            int je = (pj < pi) ? pi : pj;
            int len = je - pi + 1;
            kk_q[s] = 31 - __clz(len);
            t2_q[s] = je + 1 - (1 << kk_q[s]);
        }
    }

    // ---- GEMM: K=128, 4 k-tiles; W from LDS; key-space combine ----
    f32x4 acc[2][4];
#pragma unroll
    for (int s = 0; s < 2; ++s)
#pragma unroll
        for (int nt = 0; nt < 4; ++nt) acc[s][nt] = (f32x4){0.f, 0.f, 0.f, 0.f};

#pragma unroll
    for (int krt = 0; krt < 4; ++krt) {
        bf16x8 wfr[4];
#pragma unroll
        for (int nt = 0; nt < 4; ++nt)
            wfr[nt] = *reinterpret_cast<const bf16x8*>(&wlds[((krt * 4 + nt) * 64 + l) * 8]);

#pragma unroll
        for (int s = 0; s < 2; ++s) {
            const int pjj = 16 * s + li;
            bf16x8 av;
            if (!diag) {
                u16x8 iv = *reinterpret_cast<const u16x8*>(&intr[pjj][(krt * 4 + lg) * 8]);
                u16x8 pv = *reinterpret_cast<const u16x8*>(&pref[w][(krt * 4 + lg) * 8]);
                u16x8 ck = (krt < 2) ? kmax8(iv, pv) : kmin8(iv, pv);
                av = (bf16x8)fromkey8(ck);
            } else {
                const int c8 = krt * 4 + lg;
                const unsigned short* tab = (krt < 2) ? tabmax : tabmin;
                const int cc = (c8 & 7) * 8;
                const int kku = kk_q[s], t2u = t2_q[s];
                u16x8 va = *reinterpret_cast<const u16x8*>(&tab[(((size_t)(kku * B_ + b) * T_ + pi) << 6) + cc]);
                u16x8 vb = *reinterpret_cast<const u16x8*>(&tab[(((size_t)(kku * B_ + b) * T_ + t2u) << 6) + cc]);
                u16x8 ck = (krt < 2) ? kmax8(va, vb) : kmin8(va, vb);
                av = (bf16x8)fromkey8(ck);
            }
#pragma unroll
            for (int nt = 0; nt < 4; ++nt)
                acc[s][nt] = __builtin_amdgcn_mfma_f32_16x16x32_bf16(av, wfr[nt], acc[s][nt], 0, 0, 0);
        }
    }

    // ---- epilogue: vm = max over valid jj of (acc + g[j]); sigmoid; atomicMax ----
#pragma unroll
    for (int nt = 0; nt < 4; ++nt) {
        const int o = nt * 16 + li;
        float vm = -1e9f;
#pragma unroll
        for (int s = 0; s < 2; ++s)
#pragma unroll
            for (int r = 0; r < 4; ++r) {
                int jj = 16 * s + lg * 4 + r;
                float v = acc[s][nt][r] + gl[jj][o];
                if (!diag || (j0 + jj >= pi)) vm = fmaxf(vm, v);
            }
        vm = fmaxf(vm, __shfl_xor(vm, 16));
        vm = fmaxf(vm, __shfl_xor(vm, 32));
        if (l < 16) {
            float h = 1.0f / (1.0f + __expf(-vm));
            atomicMax((int*)out + (((size_t)(b * T_ + pi) << 6) + o), __float_as_int(h));
        }
    }
}

// ---------------------------------------------------------------------------
extern "C" void kernel_launch(void* const* d_in, const int* in_sizes, int n_in,
                              void* d_out, int out_size, void* d_ws, size_t ws_size,
                              hipStream_t stream) {
    const float* f  = (const float*)d_in[0];
    const float* W0 = (const float*)d_in[1];
    const float* b0 = (const float*)d_in[2];
    const float* W1 = (const float*)d_in[3];
    const float* b1 = (const float*)d_in[4];
    const float* W2 = (const float*)d_in[5];
    const float* b2 = (const float*)d_in[6];
    float* outp = (float*)d_out;

    // workspace layout
    unsigned short* tabmax = (unsigned short*)d_ws;               // 10*B*T*64
    unsigned short* tabmin = tabmax + 10 * B_ * T_ * 64;          // 10*B*T*64
    unsigned short* wf     = tabmin + 10 * B_ * T_ * 64;          // 3*16*64*8
    unsigned short* intra  = wf + 3 * 16 * 64 * 8;                // B*16*32*128
    float* cur1 = (float*)(intra + B_ * 16 * 32 * 128);           // [B,T,64]
    float* cur2 = cur1 + B_ * T_ * 64;                            // [B,T,64]
    float* gbuf = cur2 + B_ * T_ * 64;                            // [B,T,64]

    prep_kernel<<<dim3(43), dim3(512), 0, stream>>>(f, W0, W1, W2,
                                                    tabmax, tabmin, wf, intra);

    const dim3 pgrid(B_ * 544);
    const dim3 ggrid(B_ * T_ / 4);

    g0_kernel<<<ggrid, dim3(256), 0, stream>>>(tabmax, tabmin, W0, b0, gbuf);
    pair_kernel<<<pgrid, dim3(512), 0, stream>>>(tabmax, tabmin, intra,
                                                 wf + 0 * 8192, gbuf, cur1);

    g64_kernel<<<ggrid, dim3(256), 0, stream>>>(cur1, W1, b1, gbuf);
    pair_kernel<<<pgrid, dim3(512), 0, stream>>>(tabmax, tabmin, intra,
                                                 wf + 1 * 8192, gbuf, cur2);

    g64_kernel<<<ggrid, dim3(256), 0, stream>>>(cur2, W2, b2, gbuf);
    pair_kernel<<<pgrid, dim3(512), 0, stream>>>(tabmax, tabmin, intra,
                                                 wf + 2 * 8192, gbuf, outp);
}

// Round 19
// 75.277 us; speedup vs baseline: 1.1599x; 1.0000x over previous
//
#include <hip/hip_runtime.h>
#include <hip/hip_bf16.h>
#include <math.h>

#define B_ 2
#define T_ 512
#define D_ 64

typedef __attribute__((ext_vector_type(8))) short bf16x8;
typedef __attribute__((ext_vector_type(8))) unsigned short u16x8;
typedef __attribute__((ext_vector_type(8))) short s16x8;
typedef __attribute__((ext_vector_type(4))) float f32x4;

static __device__ __forceinline__ unsigned short f2bf(float v) {
    __hip_bfloat16 h = __float2bfloat16(v);
    return *reinterpret_cast<unsigned short*>(&h);
}
static __device__ __forceinline__ float bf2f(unsigned short u) {
    return __uint_as_float(((unsigned)u) << 16);
}
static __device__ __forceinline__ unsigned short maxbits(unsigned short a, unsigned short b) {
    float m = fmaxf(bf2f(a), bf2f(b));
    return (unsigned short)(__float_as_uint(m) >> 16);
}
static __device__ __forceinline__ unsigned short minbits(unsigned short a, unsigned short b) {
    float m = fminf(bf2f(a), bf2f(b));
    return (unsigned short)(__float_as_uint(m) >> 16);
}

// ---- order-isomorphic key space: unsigned compare on keys == float compare ----
static __device__ __forceinline__ u16x8 tokey8(u16x8 v) {
    s16x8 sr = (s16x8)v >> 15;
    u16x8 m = (u16x8)sr | (unsigned short)0x8000;
    return v ^ m;
}
static __device__ __forceinline__ u16x8 fromkey8(u16x8 k) {
    s16x8 sr = (s16x8)k >> 15;
    u16x8 m = ((u16x8)(~sr) & (unsigned short)0x7FFF) | (unsigned short)0x8000;
    return k ^ m;
}
static __device__ __forceinline__ u16x8 kmax8(u16x8 a, u16x8 b) {
    return __builtin_elementwise_max(a, b);
}
static __device__ __forceinline__ u16x8 kmin8(u16x8 a, u16x8 b) {
    return __builtin_elementwise_min(a, b);
}

// ---------------------------------------------------------------------------
// Fused prep (43 heterogeneous blocks, 512 threads):
//  [0,8)   sparse tables tab[k][b][t][c], k=0..9, bf16 KEY space
//  [8,11)  W r-part fragment pack (rows C..C+128, 16 frags/layer)
//  [11,43) intra[b][jt][jj][128] running max/min within 32-j tile, KEY space
// (No zero-init: atomicMax (int cmp) always beats the 0xAA poison, which is a
//  negative float; every (b,t,o) is covered by its diagonal tile; idempotent.)
// ---------------------------------------------------------------------------
__global__ __launch_bounds__(512) void prep_kernel(
    const float* __restrict__ f,
    const float* __restrict__ W0, const float* __restrict__ W1, const float* __restrict__ W2,
    unsigned short* __restrict__ tmax, unsigned short* __restrict__ tmin,
    unsigned short* __restrict__ wf,
    unsigned short* __restrict__ intra) {

    __shared__ unsigned short lmax[512][16];
    __shared__ unsigned short lmin[512][16];

    const int blk = blockIdx.x;
    const int tid = threadIdx.x;

    if (blk < 8) {
        const int b = blk & 1;
        const int c0 = (blk >> 1) * 16;
        const int t = tid;

        u16x8 mx[2], mn[2];
#pragma unroll
        for (int h = 0; h < 2; ++h) {
            const float* fp = &f[((size_t)(b * T_ + t) << 6) + c0 + h * 8];
#pragma unroll
            for (int e = 0; e < 8; ++e) {
                unsigned short u = f2bf(fp[e]);
                mx[h][e] = u; mn[h][e] = u;
            }
            size_t base = ((size_t)(b * T_ + t) << 6) + c0 + h * 8;
            *reinterpret_cast<u16x8*>(&tmax[base]) = tokey8(mx[h]);
            *reinterpret_cast<u16x8*>(&tmin[base]) = tokey8(mn[h]);
        }
        for (int k = 1; k <= 9; ++k) {
            *reinterpret_cast<u16x8*>(&lmax[t][0]) = mx[0];
            *reinterpret_cast<u16x8*>(&lmax[t][8]) = mx[1];
            *reinterpret_cast<u16x8*>(&lmin[t][0]) = mn[0];
            *reinterpret_cast<u16x8*>(&lmin[t][8]) = mn[1];
            __syncthreads();
            int t2 = t + (1 << (k - 1));
            if (t2 > T_ - 1) t2 = T_ - 1;
            u16x8 qx0 = *reinterpret_cast<const u16x8*>(&lmax[t2][0]);
            u16x8 qx1 = *reinterpret_cast<const u16x8*>(&lmax[t2][8]);
            u16x8 qn0 = *reinterpret_cast<const u16x8*>(&lmin[t2][0]);
            u16x8 qn1 = *reinterpret_cast<const u16x8*>(&lmin[t2][8]);
#pragma unroll
            for (int e = 0; e < 8; ++e) {
                mx[0][e] = maxbits(mx[0][e], qx0[e]);
                mx[1][e] = maxbits(mx[1][e], qx1[e]);
                mn[0][e] = minbits(mn[0][e], qn0[e]);
                mn[1][e] = minbits(mn[1][e], qn1[e]);
            }
            size_t base = ((size_t)((k * B_ + b) * T_ + t) << 6) + c0;
            *reinterpret_cast<u16x8*>(&tmax[base]) = tokey8(mx[0]);
            *reinterpret_cast<u16x8*>(&tmax[base + 8]) = tokey8(mx[1]);
            *reinterpret_cast<u16x8*>(&tmin[base]) = tokey8(mn[0]);
            *reinterpret_cast<u16x8*>(&tmin[base + 8]) = tokey8(mn[1]);
            __syncthreads();
        }
    } else if (blk < 11) {
        const int layer = blk - 8;
        const float* W = (layer == 0) ? W0 : ((layer == 1) ? W1 : W2);
        const int Coff = (layer == 0) ? 128 : 64;
        const int l = tid & 63;
#pragma unroll
        for (int q = 0; q < 2; ++q) {
            int fr = (tid >> 6) + q * 8;          // 0..15
            int kt = fr >> 2, nt = fr & 3;
#pragma unroll
            for (int e = 0; e < 8; ++e) {
                int row = Coff + kt * 32 + ((l >> 4) << 3) + e;
                int col = nt * 16 + (l & 15);
                wf[((size_t)(layer * 16 + fr) * 64 + l) * 8 + e] = f2bf(W[row * 64 + col]);
            }
        }
    } else {
        const int x = blk - 11;
        const int jt = x & 15, b = x >> 4;
        const int jj = tid >> 4, c8 = tid & 15;
        const bool ismin = c8 >= 8;
        unsigned short (*sc)[128] = reinterpret_cast<unsigned short (*)[128]>(lmax);

        const float* fp = &f[((size_t)(b * T_ + jt * 32 + jj) << 6) + (c8 & 7) * 8];
        u16x8 r;
#pragma unroll
        for (int e = 0; e < 8; ++e) r[e] = f2bf(fp[e]);

#pragma unroll
        for (int off = 1; off < 32; off <<= 1) {
            *reinterpret_cast<u16x8*>(&sc[jj][c8 * 8]) = r;
            __syncthreads();
            if (jj >= off) {
                u16x8 q = *reinterpret_cast<const u16x8*>(&sc[jj - off][c8 * 8]);
#pragma unroll
                for (int e = 0; e < 8; ++e)
                    r[e] = ismin ? minbits(r[e], q[e]) : maxbits(r[e], q[e]);
            }
            __syncthreads();
        }
        *reinterpret_cast<u16x8*>(&intra[((size_t)((b * 16 + jt) * 32 + jj) << 7) + c8 * 8]) = tokey8(r);
    }
}

// ---------------------------------------------------------------------------
// g0[b,t,o] = bias[o] + sum_{c<128} cur0[b,t,c] * W0[c][o]
// ---------------------------------------------------------------------------
__global__ __launch_bounds__(256) void g0_kernel(
    const unsigned short* __restrict__ tabmax,
    const unsigned short* __restrict__ tabmin,
    const float* __restrict__ W0, const float* __restrict__ bias,
    float* __restrict__ g) {

    __shared__ float cur_lds[4][128];

    const int tid = threadIdx.x;
    const int bt0 = blockIdx.x * 4;

    if (tid < 64) {
        int isel = tid >> 4, c8 = tid & 15;
        int bt = bt0 + isel;
        int b = bt >> 9, t = bt & 511;
        int len = T_ - t;
        int kk = 31 - __clz(len);
        int t2 = T_ - (1 << kk);
        const unsigned short* tab = (c8 < 8) ? tabmax : tabmin;
        int cc = (c8 & 7) * 8;
        u16x8 va = *reinterpret_cast<const u16x8*>(&tab[(((size_t)(kk * B_ + b) * T_ + t) << 6) + cc]);
        u16x8 vb = *reinterpret_cast<const u16x8*>(&tab[(((size_t)(kk * B_ + b) * T_ + t2) << 6) + cc]);
        u16x8 rv = fromkey8((c8 < 8) ? kmax8(va, vb) : kmin8(va, vb));
#pragma unroll
        for (int e = 0; e < 8; ++e)
            cur_lds[isel][c8 * 8 + e] = bf2f(rv[e]);
    }
    __syncthreads();

    const int r = tid >> 6, o = tid & 63;
    float s = bias[o];
#pragma unroll 8
    for (int c = 0; c < 128; ++c)
        s = fmaf(cur_lds[r][c], W0[c * 64 + o], s);
    g[((size_t)(bt0 + r) << 6) + o] = s;
}

// ---------------------------------------------------------------------------
// g[b,t,o] = bias[o] + sum_{c<64} cur[b,t,c] * W[c][o]   (fp32 cur)
// ---------------------------------------------------------------------------
__global__ __launch_bounds__(256) void g64_kernel(
    const float* __restrict__ cur, const float* __restrict__ W,
    const float* __restrict__ bias, float* __restrict__ g) {
    const int bt = blockIdx.x * 4 + (threadIdx.x >> 6);
    const int o = threadIdx.x & 63;
    float s = bias[o];
    const float* cp = &cur[(size_t)bt << 6];
#pragma unroll 8
    for (int c = 0; c < 64; ++c)
        s = fmaf(cp[c], W[c * 64 + o], s);
    g[((size_t)bt << 6) + o] = s;
}

// ---------------------------------------------------------------------------
// Pair GEMM, K = 128 (r-part only).  Block = 512 threads = 8 waves;
// (b, 8 i's, 32 j's); wave w owns row i = i0+w.  A-operand combine done in
// key space (packed u16 max/min + vector back-transform).  g added in the
// epilogue before the max; atomicMax(sigmoid) to out.  Diag blocks first.
// ---------------------------------------------------------------------------
__global__ __launch_bounds__(512) void pair_kernel(
    const unsigned short* __restrict__ tabmax,
    const unsigned short* __restrict__ tabmin,
    const unsigned short* __restrict__ intra,   // [B,16,32,128] keys
    const unsigned short* __restrict__ wf,      // layer base, 16 frags (values)
    const float* __restrict__ g,                // [B,T,64] fp32
    float* __restrict__ out) {

    // ---- decode: diag blocks first (m < 128, b-interleaved), then non-diag ----
    int m = blockIdx.x;
    int b, jt, it;
    bool diag;
    if (m < 128) {
        diag = true;
        b = m & 1;
        int idx = m >> 1;            // 0..63
        jt = idx >> 2;
        it = 4 * jt + (idx & 3);
    } else {
        diag = false;
        int m2 = m - 128;
        b = m2 & 1;
        int m3 = m2 >> 1;            // 0..479
        jt = 1;
        while (m3 >= 2 * jt * (jt + 1)) ++jt;     // <=14 iters
        it = m3 - 2 * jt * (jt - 1);              // 0 .. 4*jt-1
    }
    const int i0 = it * 8, j0 = jt * 32;

    const int tid = threadIdx.x;
    const int l = tid & 63, w = tid >> 6;         // w = 0..7
    const int lg = l >> 4, li = l & 15;
    const int pi = i0 + w;

    __shared__ unsigned short intr[32][136];
    __shared__ unsigned short pref[8][136];
    __shared__ unsigned short wlds[16 * 64 * 8];   // 16 KB
    __shared__ float gl[32][68];

    // ---- stage W fragments (contiguous, 1024 chunks) ----
#pragma unroll
    for (int q = 0; q < 2; ++q) {
        int idx = q * 512 + tid;
        u16x8 v = *reinterpret_cast<const u16x8*>(&wf[(size_t)idx * 8]);
        *reinterpret_cast<u16x8*>(&wlds[idx * 8]) = v;
    }

    // ---- stage g tile [32 j][64 o] (512 float4 chunks) ----
    {
        int jj = tid >> 4, c4 = tid & 15;
        float4 v = *reinterpret_cast<const float4*>(&g[((size_t)(b * T_ + j0 + jj) << 6) + c4 * 4]);
        *reinterpret_cast<float4*>(&gl[jj][c4 * 4]) = v;
    }

    if (!diag) {
        // ---- intra tile: contiguous copy (512 chunks), key space ----
        {
            int jj = tid >> 4, c8 = tid & 15;
            u16x8 v = *reinterpret_cast<const u16x8*>(
                &intra[((size_t)((b * 16 + jt) * 32 + jj) << 7) + c8 * 8]);
            *reinterpret_cast<u16x8*>(&intr[jj][c8 * 8]) = v;
        }
        // ---- prefix queries: 8 i's x 16 chunks, range [i, j0-1], key space ----
        if (tid < 128) {
            int isel = tid >> 4, c8 = tid & 15;
            int i = i0 + isel;
            int len = j0 - i;                  // >= 1 (non-diag)
            int kk = 31 - __clz(len);
            int t2 = j0 - (1 << kk);
            const unsigned short* tab = (c8 < 8) ? tabmax : tabmin;
            int cc = (c8 & 7) * 8;
            u16x8 va = *reinterpret_cast<const u16x8*>(&tab[(((size_t)(kk * B_ + b) * T_ + i) << 6) + cc]);
            u16x8 vb = *reinterpret_cast<const u16x8*>(&tab[(((size_t)(kk * B_ + b) * T_ + t2) << 6) + cc]);
            u16x8 r = (c8 < 8) ? kmax8(va, vb) : kmin8(va, vb);
            *reinterpret_cast<u16x8*>(&pref[isel][c8 * 8]) = r;
        }
    }
    __syncthreads();

    // ---- diag query params (per s) ----
    int kk_q[2], t2_q[2];
    if (diag) {
#pragma unroll
        for (int s = 0; s < 2; ++s) {
            int pj = j0 + 16 * s + li;
            int je = (pj < pi) ? pi : pj;
            int len = je - pi + 1;
            kk_q[s] = 31 - __clz(len);
            t2_q[s] = je + 1 - (1 << kk_q[s]);
        }
    }

    // ---- GEMM: K=128, 4 k-tiles; W from LDS; key-space combine ----
    f32x4 acc[2][4];
#pragma unroll
    for (int s = 0; s < 2; ++s)
#pragma unroll
        for (int nt = 0; nt < 4; ++nt) acc[s][nt] = (f32x4){0.f, 0.f, 0.f, 0.f};

#pragma unroll
    for (int krt = 0; krt < 4; ++krt) {
        bf16x8 wfr[4];
#pragma unroll
        for (int nt = 0; nt < 4; ++nt)
            wfr[nt] = *reinterpret_cast<const bf16x8*>(&wlds[((krt * 4 + nt) * 64 + l) * 8]);

#pragma unroll
        for (int s = 0; s < 2; ++s) {
            const int pjj = 16 * s + li;
            bf16x8 av;
            if (!diag) {
                u16x8 iv = *reinterpret_cast<const u16x8*>(&intr[pjj][(krt * 4 + lg) * 8]);
                u16x8 pv = *reinterpret_cast<const u16x8*>(&pref[w][(krt * 4 + lg) * 8]);
                u16x8 ck = (krt < 2) ? kmax8(iv, pv) : kmin8(iv, pv);
                av = (bf16x8)fromkey8(ck);
            } else {
                const int c8 = krt * 4 + lg;
                const unsigned short* tab = (krt < 2) ? tabmax : tabmin;
                const int cc = (c8 & 7) * 8;
                const int kku = kk_q[s], t2u = t2_q[s];
                u16x8 va = *reinterpret_cast<const u16x8*>(&tab[(((size_t)(kku * B_ + b) * T_ + pi) << 6) + cc]);
                u16x8 vb = *reinterpret_cast<const u16x8*>(&tab[(((size_t)(kku * B_ + b) * T_ + t2u) << 6) + cc]);
                u16x8 ck = (krt < 2) ? kmax8(va, vb) : kmin8(va, vb);
                av = (bf16x8)fromkey8(ck);
            }
#pragma unroll
            for (int nt = 0; nt < 4; ++nt)
                acc[s][nt] = __builtin_amdgcn_mfma_f32_16x16x32_bf16(av, wfr[nt], acc[s][nt], 0, 0, 0);
        }
    }

    // ---- epilogue: vm = max over valid jj of (acc + g[j]); sigmoid; atomicMax ----
#pragma unroll
    for (int nt = 0; nt < 4; ++nt) {
        const int o = nt * 16 + li;
        float vm = -1e9f;
#pragma unroll
        for (int s = 0; s < 2; ++s)
#pragma unroll
            for (int r = 0; r < 4; ++r) {
                int jj = 16 * s + lg * 4 + r;
                float v = acc[s][nt][r] + gl[jj][o];
                if (!diag || (j0 + jj >= pi)) vm = fmaxf(vm, v);
            }
        vm = fmaxf(vm, __shfl_xor(vm, 16));
        vm = fmaxf(vm, __shfl_xor(vm, 32));
        if (l < 16) {
            float h = 1.0f / (1.0f + __expf(-vm));
            atomicMax((int*)out + (((size_t)(b * T_ + pi) << 6) + o), __float_as_int(h));
        }
    }
}

// ---------------------------------------------------------------------------
extern "C" void kernel_launch(void* const* d_in, const int* in_sizes, int n_in,
                              void* d_out, int out_size, void* d_ws, size_t ws_size,
                              hipStream_t stream) {
    const float* f  = (const float*)d_in[0];
    const float* W0 = (const float*)d_in[1];
    const float* b0 = (const float*)d_in[2];
    const float* W1 = (const float*)d_in[3];
    const float* b1 = (const float*)d_in[4];
    const float* W2 = (const float*)d_in[5];
    const float* b2 = (const float*)d_in[6];
    float* outp = (float*)d_out;

    // workspace layout
    unsigned short* tabmax = (unsigned short*)d_ws;               // 10*B*T*64
    unsigned short* tabmin = tabmax + 10 * B_ * T_ * 64;          // 10*B*T*64
    unsigned short* wf     = tabmin + 10 * B_ * T_ * 64;          // 3*16*64*8
    unsigned short* intra  = wf + 3 * 16 * 64 * 8;                // B*16*32*128
    float* cur1 = (float*)(intra + B_ * 16 * 32 * 128);           // [B,T,64]
    float* cur2 = cur1 + B_ * T_ * 64;                            // [B,T,64]
    float* gbuf = cur2 + B_ * T_ * 64;                            // [B,T,64]

    prep_kernel<<<dim3(43), dim3(512), 0, stream>>>(f, W0, W1, W2,
                                                    tabmax, tabmin, wf, intra);

    const dim3 pgrid(B_ * 544);
    const dim3 ggrid(B_ * T_ / 4);

    g0_kernel<<<ggrid, dim3(256), 0, stream>>>(tabmax, tabmin, W0, b0, gbuf);
    pair_kernel<<<pgrid, dim3(512), 0, stream>>>(tabmax, tabmin, intra,
                                                 wf + 0 * 8192, gbuf, cur1);

    g64_kernel<<<ggrid, dim3(256), 0, stream>>>(cur1, W1, b1, gbuf);
    pair_kernel<<<pgrid, dim3(512), 0, stream>>>(tabmax, tabmin, intra,
                                                 wf + 1 * 8192, gbuf, cur2);

    g64_kernel<<<ggrid, dim3(256), 0, stream>>>(cur2, W2, b2, gbuf);
    pair_kernel<<<pgrid, dim3(512), 0, stream>>>(tabmax, tabmin, intra,
                                                 wf + 2 * 8192, gbuf, outp);
}